// Round 1
// baseline (230.778 us; speedup 1.0000x reference)
//
#include <hip/hip_runtime.h>
#include <hip/hip_bf16.h>

#define W512   512
#define PATCH  32
#define NP     16        // patches per side (512/32)
#define L      256       // NP*NP patches per image
#define NCH    128       // descriptor channels
#define NPIX   1024      // PATCH*PATCH

__device__ __forceinline__ float wave_max(float v) {
    #pragma unroll
    for (int o = 32; o; o >>= 1) v = fmaxf(v, __shfl_xor(v, o, 64));
    return v;
}
__device__ __forceinline__ float wave_sum(float v) {
    #pragma unroll
    for (int o = 32; o; o >>= 1) v += __shfl_xor(v, o, 64);
    return v;
}

__global__ __launch_bounds__(256)
void keypoint_kernel(const float* __restrict__ det,
                     const float* __restrict__ wsc,
                     const float* __restrict__ desc,
                     float* __restrict__ out) {
    __shared__ float att[NPIX];   // softmax weights for this patch
    __shared__ float red[12];     // cross-wave reduction scratch

    const int blk = blockIdx.x;       // b*L + l
    const int b   = blk >> 8;         // / 256
    const int l   = blk & 255;
    const int hp  = l >> 4;           // patch-grid row
    const int wp  = l & 15;           // patch-grid col

    const int t    = threadIdx.x;
    const int wave = t >> 6;
    const int lane = t & 63;
    const int r    = t >> 3;          // row within patch (ki)
    const int q    = t & 7;           // float4 index within row

    const int row = hp * PATCH + r;       // global image row (v)
    const int col = wp * PATCH + q * 4;   // global image col (u), first of 4

    const size_t pix = (size_t)b * (W512 * W512) + (size_t)row * W512 + col;

    // ---- softmax over the 1024-pixel patch (TEMP = 1) ----
    const float4 d4 = *(const float4*)(det + pix);

    float m = fmaxf(fmaxf(d4.x, d4.y), fmaxf(d4.z, d4.w));
    m = wave_max(m);
    if (lane == 0) red[wave] = m;
    __syncthreads();
    m = fmaxf(fmaxf(red[0], red[1]), fmaxf(red[2], red[3]));

    float e0 = expf(d4.x - m);
    float e1 = expf(d4.y - m);
    float e2 = expf(d4.z - m);
    float e3 = expf(d4.w - m);

    float s = wave_sum(e0 + e1 + e2 + e3);
    if (lane == 0) red[4 + wave] = s;   // disjoint from red[0..3] still being read
    __syncthreads();
    s = red[4] + red[5] + red[6] + red[7];
    const float inv = 1.0f / s;
    e0 *= inv; e1 *= inv; e2 *= inv; e3 *= inv;

    // stage att into LDS: element k = 4*t (+j), contiguous float4 store
    *(float4*)(att + 4 * t) = make_float4(e0, e1, e2, e3);

    // ---- expected coords + weighted score (fused reductions) ----
    const float4 w4 = *(const float4*)(wsc + pix);
    float pu = e0 * (float)(col)     + e1 * (float)(col + 1)
             + e2 * (float)(col + 2) + e3 * (float)(col + 3);
    float pv = (e0 + e1 + e2 + e3) * (float)row;
    float ps = e0 * w4.x + e1 * w4.y + e2 * w4.z + e3 * w4.w;

    pu = wave_sum(pu);
    pv = wave_sum(pv);
    ps = wave_sum(ps);
    __syncthreads();                 // everyone done reading red[4..7]; att stores done
    if (lane == 0) { red[wave] = pu; red[4 + wave] = pv; red[8 + wave] = ps; }
    __syncthreads();                 // red + att both ready for all threads
    if (t == 0) {
        out[blk * 2 + 0]    = red[0] + red[1] + red[2]  + red[3];   // expected_u
        out[blk * 2 + 1]    = red[4] + red[5] + red[6]  + red[7];   // expected_v
        out[2 * (8 * L) + blk] = red[8] + red[9] + red[10] + red[11]; // score @ off 4096
    }

    // ---- descriptor pooling: wave w owns channels w, w+4, ... ----
    const int lr = lane >> 3;        // base row for this lane
    const int lq = lane & 7;
    const size_t dbase = ((size_t)(b * NCH) * W512 + (size_t)(hp * PATCH)) * W512
                       + (size_t)(wp * PATCH) + lq * 4;
    float* __restrict__ outd = out + 4096 + 2048;

    for (int c = wave; c < NCH; c += 4) {
        const float* dp = desc + dbase + (size_t)c * (W512 * W512);
        float acc = 0.f;
        #pragma unroll
        for (int rr = 0; rr < 4; ++rr) {
            const int prow = lr + rr * 8;
            const float4 dv = *(const float4*)(dp + (size_t)prow * W512);
            const float4 av = *(const float4*)(att + prow * 32 + lq * 4);
            acc += dv.x * av.x + dv.y * av.y + dv.z * av.z + dv.w * av.w;
        }
        acc = wave_sum(acc);
        if (lane == 0) outd[(b * NCH + c) * L + l] = acc;
    }
}

extern "C" void kernel_launch(void* const* d_in, const int* in_sizes, int n_in,
                              void* d_out, int out_size, void* d_ws, size_t ws_size,
                              hipStream_t stream) {
    const float* det  = (const float*)d_in[0];
    const float* wsc  = (const float*)d_in[1];
    const float* desc = (const float*)d_in[2];
    float* out = (float*)d_out;

    dim3 grid(8 * L);   // one block per (batch, patch)
    dim3 block(256);
    keypoint_kernel<<<grid, block, 0, stream>>>(det, wsc, desc, out);
}

// Round 2
// 196.841 us; speedup vs baseline: 1.1724x; 1.1724x over previous
//
#include <hip/hip_runtime.h>
#include <hip/hip_bf16.h>

#define W512   512
#define PATCH  32
#define NP     16        // patches per side
#define L      256       // patches per image
#define NCH    128       // descriptor channels
#define NPIX   1024      // pixels per patch
#define PLANE  (W512 * W512)

__device__ __forceinline__ float wave_max(float v) {
    #pragma unroll
    for (int o = 32; o; o >>= 1) v = fmaxf(v, __shfl_xor(v, o, 64));
    return v;
}
__device__ __forceinline__ float wave_sum(float v) {
    #pragma unroll
    for (int o = 32; o; o >>= 1) v += __shfl_xor(v, o, 64);
    return v;
}

// ---------------- kernel 1: softmax att + coords + scores ----------------
__global__ __launch_bounds__(256)
void att_kernel(const float* __restrict__ det,
                const float* __restrict__ wsc,
                float* __restrict__ out,
                float* __restrict__ attws) {
    __shared__ float red[12];

    const int blk = blockIdx.x;       // b*L + l
    const int b   = blk >> 8;
    const int l   = blk & 255;
    const int hp  = l >> 4;
    const int wp  = l & 15;

    const int t    = threadIdx.x;
    const int wave = t >> 6;
    const int lane = t & 63;
    const int r    = t >> 3;          // row within patch
    const int q    = t & 7;           // float4 index within row

    const int row = hp * PATCH + r;
    const int col = wp * PATCH + q * 4;
    const size_t pix = (size_t)b * PLANE + (size_t)row * W512 + col;

    const float4 d4 = *(const float4*)(det + pix);

    float m = fmaxf(fmaxf(d4.x, d4.y), fmaxf(d4.z, d4.w));
    m = wave_max(m);
    if (lane == 0) red[wave] = m;
    __syncthreads();
    m = fmaxf(fmaxf(red[0], red[1]), fmaxf(red[2], red[3]));

    float e0 = expf(d4.x - m);
    float e1 = expf(d4.y - m);
    float e2 = expf(d4.z - m);
    float e3 = expf(d4.w - m);

    float s = wave_sum(e0 + e1 + e2 + e3);
    if (lane == 0) red[4 + wave] = s;
    __syncthreads();
    s = red[4] + red[5] + red[6] + red[7];
    const float inv = 1.0f / s;
    e0 *= inv; e1 *= inv; e2 *= inv; e3 *= inv;

    // normalized attention in image layout (same address as det read)
    *(float4*)(attws + pix) = make_float4(e0, e1, e2, e3);

    const float4 w4 = *(const float4*)(wsc + pix);
    float pu = e0 * (float)(col)     + e1 * (float)(col + 1)
             + e2 * (float)(col + 2) + e3 * (float)(col + 3);
    float pv = (e0 + e1 + e2 + e3) * (float)row;
    float ps = e0 * w4.x + e1 * w4.y + e2 * w4.z + e3 * w4.w;

    pu = wave_sum(pu);
    pv = wave_sum(pv);
    ps = wave_sum(ps);
    __syncthreads();
    if (lane == 0) { red[wave] = pu; red[4 + wave] = pv; red[8 + wave] = ps; }
    __syncthreads();
    if (t == 0) {
        out[blk * 2 + 0]       = red[0] + red[1] + red[2]  + red[3];
        out[blk * 2 + 1]       = red[4] + red[5] + red[6]  + red[7];
        out[2 * (8 * L) + blk] = red[8] + red[9] + red[10] + red[11];
    }
}

// ---------------- kernel 2: strip-sequential descriptor pooling ----------------
// block = one (b, hp, channel-group-of-8); wave owns 2 channels and streams
// the strip's contiguous 64 KiB region of each plane.
__global__ __launch_bounds__(256)
void pool_kernel(const float* __restrict__ desc,
                 const float* __restrict__ attws,
                 float* __restrict__ outd) {
    const int bid   = blockIdx.x;     // 0..2047; cg in high bits -> same-strip
    const int cg    = bid >> 7;       //          blocks co-locate per XCD (bid%8)
    const int strip = bid & 127;      // b*16 + hp
    const int b     = strip >> 4;
    const int hp    = strip & 15;

    const int t    = threadIdx.x;
    const int wave = t >> 6;
    const int lane = t & 63;
    const int ch   = cg * 8 + wave * 2;

    const float* ap  = attws + ((size_t)b * W512 + hp * PATCH) * W512 + lane * 4;
    const float* dp0 = desc + (((size_t)(b * NCH + ch)) * W512 + hp * PATCH) * W512 + lane * 4;
    const float* dp1 = dp0 + PLANE;

    float a00 = 0.f, a01 = 0.f, a10 = 0.f, a11 = 0.f;
    #pragma unroll 4
    for (int r = 0; r < PATCH; ++r) {
        const int off = r * W512;
        const float4 av0 = *(const float4*)(ap  + off);
        const float4 av1 = *(const float4*)(ap  + off + 256);
        const float4 d00 = *(const float4*)(dp0 + off);
        const float4 d01 = *(const float4*)(dp0 + off + 256);
        const float4 d10 = *(const float4*)(dp1 + off);
        const float4 d11 = *(const float4*)(dp1 + off + 256);
        a00 += av0.x * d00.x + av0.y * d00.y + av0.z * d00.z + av0.w * d00.w;
        a01 += av1.x * d01.x + av1.y * d01.y + av1.z * d01.z + av1.w * d01.w;
        a10 += av0.x * d10.x + av0.y * d10.y + av0.z * d10.z + av0.w * d10.w;
        a11 += av1.x * d11.x + av1.y * d11.y + av1.z * d11.z + av1.w * d11.w;
    }

    // reduce across the 8 lanes sharing one patch column-group
    #pragma unroll
    for (int o = 1; o <= 4; o <<= 1) {
        a00 += __shfl_xor(a00, o, 64);
        a01 += __shfl_xor(a01, o, 64);
        a10 += __shfl_xor(a10, o, 64);
        a11 += __shfl_xor(a11, o, 64);
    }

    if ((lane & 7) == 0) {
        const int wp0 = lane >> 3;
        float* o0 = outd + ((size_t)(b * NCH + ch)) * L + hp * NP;
        o0[wp0]     = a00;
        o0[8 + wp0] = a01;
        float* o1 = o0 + L;
        o1[wp0]     = a10;
        o1[8 + wp0] = a11;
    }
}

extern "C" void kernel_launch(void* const* d_in, const int* in_sizes, int n_in,
                              void* d_out, int out_size, void* d_ws, size_t ws_size,
                              hipStream_t stream) {
    const float* det  = (const float*)d_in[0];
    const float* wsc  = (const float*)d_in[1];
    const float* desc = (const float*)d_in[2];
    float* out   = (float*)d_out;
    float* attws = (float*)d_ws;      // 8 MiB attention map, image layout

    att_kernel<<<dim3(8 * L), dim3(256), 0, stream>>>(det, wsc, out, attws);
    pool_kernel<<<dim3(2048), dim3(256), 0, stream>>>(desc, attws, out + 4096 + 2048);
}